// Round 8
// baseline (422.138 us; speedup 1.0000x reference)
//
#include <hip/hip_runtime.h>
#include <math.h>

#define HDIM 4096
#define NEXP 64
#define NTOK 16384
#define MBLK 32            // tokens per block (one 32-wide MFMA tile)
#define STEPS 128          // k8-steps per wave (K split 4 ways across waves)
#define PD 4               // prefetch depth (steps in flight)
#define CSTRIDE 68
#define GS_FLOATS 262144   // 1 MB pre-split gate in workspace

typedef float v4f __attribute__((ext_vector_type(4)));
typedef short bh4 __attribute__((ext_vector_type(4)));     // 4 x bf16 (MFMA operand)
typedef float f32x16 __attribute__((ext_vector_type(16))); // MFMA accumulator

#if defined(__has_builtin)
#if __has_builtin(__builtin_amdgcn_mfma_f32_32x32x8bf16_1k)
#define HAVE_MFMA_BUILTIN 1
#endif
#endif

__device__ __forceinline__ f32x16 mfma_bf16(bh4 a, bh4 b, f32x16 c) {
#ifdef HAVE_MFMA_BUILTIN
    return __builtin_amdgcn_mfma_f32_32x32x8bf16_1k(a, b, c, 0, 0, 0);
#else
    asm("v_mfma_f32_32x32x8_bf16 %0, %1, %2, %0" : "+v"(c) : "v"(a), "v"(b));
    return c;
#endif
}

// 2-way bf16 split (RNE both) — EXACTLY the R7-passing numerics.
__device__ __forceinline__ void split2(float v, unsigned short& h0,
                                       unsigned short& h1) {
    unsigned b0 = __builtin_bit_cast(unsigned, v);
    unsigned r0 = (b0 + 0x7FFFu + ((b0 >> 16) & 1u)) & 0xFFFF0000u;
    h0 = (unsigned short)(r0 >> 16);
    float v1 = v - __builtin_bit_cast(float, r0);      // exact
    unsigned b1 = __builtin_bit_cast(unsigned, v1);
    h1 = (unsigned short)((b1 + 0x7FFFu + ((b1 >> 16) & 1u)) >> 16);  // RNE
}

__device__ __forceinline__ uint2 pack4(const unsigned short* h) {
    return make_uint2((unsigned)h[0] | ((unsigned)h[1] << 16),
                      (unsigned)h[2] | ((unsigned)h[3] << 16));
}

// Pre-kernel (unchanged from R7): split gate into 2 bf16 planes in MFMA
// B-fragment order gs[((k8g*2+p)*2+ntp)*64 + lane].
__global__ __launch_bounds__(256) void gate_presplit(
    const float* __restrict__ gate, uint2* __restrict__ gs)
{
    const int f = blockIdx.x * 256 + threadIdx.x;   // 65536 = 512 k8g x 2 ntp x 64 lane
    const int l = f & 63;
    const int ntp = (f >> 6) & 1;
    const int k8g = f >> 7;
    const int e = ntp * 32 + (l & 31);
    const int k = k8g * 8 + (l >> 5) * 4;
    v4f x = *(const v4f*)&gate[(size_t)e * HDIM + k];
    float xv[4] = {x.x, x.y, x.z, x.w};
    unsigned short lo[4], hi[4];
#pragma unroll
    for (int j = 0; j < 4; ++j) split2(xv[j], lo[j], hi[j]);
    gs[((size_t)(k8g * 2 + 0) * 2 + ntp) * 64 + l] = pack4(lo);
    gs[((size_t)(k8g * 2 + 1) * 2 + ntp) * 64 + l] = pack4(hi);
}

// R8 main: barrier-free streaming MFMA. 512 blocks x 512 threads (8 waves =
// ntp(2 expert halves) x h(4 K-quarters)), 2 blocks/CU -> 16 waves/CU.
// R7 post-mortem (~127us): A round-tripped through LDS behind a per-chunk
// lockstep barrier at 8 waves/CU. R8: the MFMA A-fragment is row-contiguous
// per lane (tok=l&31, k=k8*8+(l>>5)*4+j), so each lane loads its fragment
// DIRECTLY from global as one dwordx4 per k8-step; split2 in registers; no
// LDS, no barrier in the main loop. Adjacent steps consume adjacent 32-B
// half-lines (L1/L2 absorb granularity; NO nt bit — caching is load-bearing).
// Explicit PD=4 prefetch (statically indexed) covers L2/HBM latency.
// Cross-wave K-reduction once at the end via Pacc.
__global__ __launch_bounds__(512, 2) void router_main(
    const float* __restrict__ hidden,
    const uint2* __restrict__ gs,
    float* __restrict__ out_rw,
    float* __restrict__ out_sel,
    float* __restrict__ psum_g,
    float* __restrict__ cnt_g,
    float* __restrict__ zsum_g)
{
    __shared__ float Pacc[3][2][16][64];   // h=1..3 partials, 24 KB
    __shared__ float C_lds[MBLK * CSTRIDE];
    __shared__ float rden[MBLK];
    __shared__ unsigned hist[NEXP];

    const int t = threadIdx.x;
    const int lane = t & 63;
    const int wave = __builtin_amdgcn_readfirstlane(t >> 6);
    const int ntp = wave & 1, h = wave >> 1;          // h in 0..3
    const int m0 = blockIdx.x * MBLK;

    const int tok = lane & 31;
    const int kj = (lane >> 5) * 4;

    // A: lane's fragment for step s = floats [(m0+tok)*4096 + h*1024 + s*8 + kj, +4)
    const float* Abase = hidden + (size_t)(m0 + tok) * HDIM + h * (HDIM / 4) + kj;
    // B: k8g = h*128 + s; gs idx = k8g*256 + p*128 + ntp*64 + lane
    const uint2* Bbase = gs + (size_t)h * 128 * 256 + ntp * 64 + lane;

    f32x16 acc{};

    v4f apf[PD];
    uint2 b0f[PD], b1f[PD];
#pragma unroll
    for (int i = 0; i < PD; ++i) {
        apf[i] = *(const v4f*)(Abase + (size_t)i * 8);
        b0f[i] = Bbase[(size_t)i * 256];
        b1f[i] = Bbase[(size_t)i * 256 + 128];
    }

    for (int s = 0; s < STEPS; s += PD) {
#pragma unroll
        for (int u = 0; u < PD; ++u) {
            v4f a = apf[u];
            uint2 b0 = b0f[u], b1 = b1f[u];
            // issue loads for step s+u+PD (clamped tail; garbage never used)
            int sn = s + u + PD;
            sn = (sn < STEPS) ? sn : (STEPS - 1);
            apf[u] = *(const v4f*)(Abase + (size_t)sn * 8);
            b0f[u] = Bbase[(size_t)sn * 256];
            b1f[u] = Bbase[(size_t)sn * 256 + 128];
            // split A fragment in registers (R7-proven numerics)
            float av[4] = {a.x, a.y, a.z, a.w};
            unsigned short lo[4], hi[4];
#pragma unroll
            for (int j = 0; j < 4; ++j) split2(av[j], lo[j], hi[j]);
            bh4 a0 = __builtin_bit_cast(bh4, pack4(lo));
            bh4 a1 = __builtin_bit_cast(bh4, pack4(hi));
            bh4 bb0 = __builtin_bit_cast(bh4, b0);
            bh4 bb1 = __builtin_bit_cast(bh4, b1);
            acc = mfma_bf16(a0, bb0, acc);
            acc = mfma_bf16(a1, bb0, acc);
            acc = mfma_bf16(a0, bb1, acc);
            acc = mfma_bf16(a1, bb1, acc);
        }
    }

    // MFMA -> VALU/LDS hazard guard
    asm volatile("s_nop 7\n\ts_nop 7" :::);

    if (h > 0) {
#pragma unroll
        for (int r = 0; r < 16; ++r) Pacc[h - 1][ntp][r][lane] = acc[r];
    }
    if (t < NEXP) hist[t] = 0u;
    __syncthreads();
    if (h == 0) {
        // D layout [R6/R7-verified]: col=lane&31, row=(r&3)+8*(r>>2)+4*(lane>>5)
#pragma unroll
        for (int r = 0; r < 16; ++r) {
            float x = acc[r] + Pacc[0][ntp][r][lane] + Pacc[1][ntp][r][lane]
                             + Pacc[2][ntp][r][lane];
            const int to = (r & 3) + 8 * (r >> 2) + 4 * (lane >> 5);
            const int e = ntp * 32 + (lane & 31);
            C_lds[to * CSTRIDE + e] = x;
        }
    }
    __syncthreads();

    if (wave != 0) return;   // epilogue on wave 0 (lanes 0..31 = tokens)

    float z = 0.f;
    if (lane < MBLK) {
        // top-2 (strict >, ascending e => ties pick lower index, matches jax)
        float v1 = -INFINITY, v2 = -INFINITY;
        int i1 = 0, i2 = 0;
        for (int e = 0; e < NEXP; ++e) {
            float v = C_lds[lane * CSTRIDE + e];
            if (v > v1)      { v2 = v1; i2 = i1; v1 = v; i1 = e; }
            else if (v > v2) { v2 = v;  i2 = e; }
        }
        atomicAdd(&hist[i1], 1u);
        atomicAdd(&hist[i2], 1u);

        float d = 0.f;
        for (int e = 0; e < NEXP; ++e) {
            float ev = expf(C_lds[lane * CSTRIDE + e] - v1);
            C_lds[lane * CSTRIDE + e] = ev;
            d += ev;
        }
        rden[lane] = 1.0f / d;
        float lse = v1 + logf(d);
        z = lse * lse;

        float e2 = expf(v2 - v1);
        float w2 = e2 / (1.f + e2);
        float w1 = 1.f - w2;
        int tk = m0 + lane;
        out_rw[2 * tk + 0] = w1;
        out_rw[2 * tk + 1] = w2;
        out_sel[2 * tk + 0] = (float)i1;
        out_sel[2 * tk + 1] = (float)i2;
    }

#pragma unroll
    for (int off = 32; off > 0; off >>= 1) z += __shfl_down(z, off);
    if (lane == 0) atomicAdd(zsum_g, z);

    // per-expert prob sums over this block's 32 tokens (lane = expert)
    float ps = 0.f;
    for (int m = 0; m < MBLK; ++m)
        ps += C_lds[m * CSTRIDE + lane] * rden[m];
    atomicAdd(&psum_g[lane], ps);
    atomicAdd(&cnt_g[lane], (float)hist[lane]);
}

__global__ void router_final(const float* __restrict__ ws, float* __restrict__ out_loss)
{
    int e = threadIdx.x;  // 64 threads
    const float inv = 1.0f / (float)NTOK;
    float p = (ws[64 + e] * inv) * (ws[e] * inv);
#pragma unroll
    for (int off = 32; off > 0; off >>= 1) p += __shfl_down(p, off);
    if (e == 0)
        out_loss[0] = 0.01f * (64.f * p) + 0.001f * (ws[128] * inv);
}

extern "C" void kernel_launch(void* const* d_in, const int* in_sizes, int n_in,
                              void* d_out, int out_size, void* d_ws, size_t ws_size,
                              hipStream_t stream) {
    const float* hidden = (const float*)d_in[0];   // [4,4096,4096] fp32
    const float* gate   = (const float*)d_in[1];   // [64,4096] fp32
    float* out = (float*)d_out;                    // 65537 floats
    float* ws  = (float*)d_ws;                     // gsplit 1MB | psum[64] cnt[64] zsum[1]
    float* stats = ws + GS_FLOATS;

    hipMemsetAsync(stats, 0, 129 * sizeof(float), stream);
    gate_presplit<<<dim3(256), dim3(256), 0, stream>>>(gate, (uint2*)ws);
    router_main<<<dim3(NTOK / MBLK), dim3(512), 0, stream>>>(
        hidden, (const uint2*)ws,
        out,                 // routing weights
        out + NTOK * 2,      // selected experts (as floats)
        stats, stats + 64, stats + 128);
    router_final<<<dim3(1), dim3(64), 0, stream>>>(stats, out + NTOK * 4);
}